// Round 2
// baseline (3388.114 us; speedup 1.0000x reference)
//
#include <hip/hip_runtime.h>
#include <math.h>

#define BN_EPS 1e-5f

// ---------- helpers ----------

__device__ __forceinline__ float siluf(float v) {
    return v / (1.0f + __expf(-v));
}

// Cubic B-spline basis (4 funcs) on uniform knots g[j] = 2*j - 7, j=0..7.
// Closed form: x lies in knot interval j = floor((x+7)/2), local t in [0,1).
// b[i] = segment (j-i) of the standard uniform cubic B-spline, else 0.
__device__ __forceinline__ void bspline4(float x, float b[4]) {
    float u = (x + 7.0f) * 0.5f;
    float jf = floorf(u);
    float t = u - jf;
    float t2 = t * t, t3 = t2 * t;
    float omt = 1.0f - t;
    float v0 = t3 * (1.0f / 6.0f);                                   // seg 0
    float v1 = (-3.0f * t3 + 3.0f * t2 + 3.0f * t + 1.0f) * (1.0f / 6.0f); // seg 1
    float v2 = (3.0f * t3 - 6.0f * t2 + 4.0f) * (1.0f / 6.0f);       // seg 2
    float v3 = omt * omt * omt * (1.0f / 6.0f);                      // seg 3
    int j = (int)jf;
#pragma unroll
    for (int i = 0; i < 4; ++i) {
        int d = j - i;
        float r = (d == 0) ? v0 : (d == 1) ? v1 : (d == 2) ? v2 : (d == 3) ? v3 : 0.0f;
        b[i] = r;
    }
}

// ---------- conv1: [1024,3,32,32] -> h1 [1024,32,31,31], + channel stats ----------
// 984064 patches, 256/block (stride-64 ownership of 4 patches), 3844 blocks.

__global__ __launch_bounds__(256) void conv1_kernel(
        const float* __restrict__ x, const float* __restrict__ bw,
        const float* __restrict__ sw, float* __restrict__ h1,
        float* __restrict__ stats) {
    __shared__ float Wl[12 * 32 * 8];  // [i][o][k], k padded 5->8 for b128 align
    for (int j = threadIdx.x; j < 12 * 32 * 5; j += 256) {
        int i = j / 160;
        int r = j - i * 160;
        int o = r / 5;
        int k = r - o * 5;
        Wl[(i * 32 + o) * 8 + k] = (k == 0) ? bw[o * 12 + i]
                                            : sw[(o * 12 + i) * 4 + k - 1];
    }
    __syncthreads();

    int lane = threadIdx.x & 63, og = threadIdx.x >> 6;  // og: 8 outputs each
    int pbase = blockIdx.x * 256 + lane;
    int pb[4], py[4], px[4];
#pragma unroll
    for (int r = 0; r < 4; ++r) {
        int p = pbase + 64 * r;
        pb[r] = p / 961;
        int q = p - pb[r] * 961;
        py[r] = q / 31;
        px[r] = q - py[r] * 31;
    }
    float acc[4][8];
#pragma unroll
    for (int r = 0; r < 4; ++r)
#pragma unroll
        for (int oo = 0; oo < 8; ++oo) acc[r][oo] = 0.0f;

#pragma unroll 1
    for (int i = 0; i < 12; ++i) {
        int c = i >> 2, dy = (i >> 1) & 1, dx = i & 1;
        float v[4];
#pragma unroll
        for (int r = 0; r < 4; ++r)
            v[r] = x[(pb[r] * 3 + c) * 1024 + (py[r] + dy) * 32 + px[r] + dx];
        float e[4][5];
#pragma unroll
        for (int r = 0; r < 4; ++r) {
            e[r][0] = siluf(v[r]);
            bspline4(v[r], &e[r][1]);
        }
#pragma unroll
        for (int oo = 0; oo < 8; ++oo) {
            const float* wp = &Wl[(i * 32 + og * 8 + oo) * 8];
            float4 w0 = *(const float4*)wp;
            float w4v = wp[4];
#pragma unroll
            for (int r = 0; r < 4; ++r) {
                acc[r][oo] += e[r][0] * w0.x + e[r][1] * w0.y + e[r][2] * w0.z
                            + e[r][3] * w0.w + e[r][4] * w4v;
            }
        }
    }

    // write h1 (coalesced: consecutive lanes -> consecutive patches)
#pragma unroll
    for (int oo = 0; oo < 8; ++oo) {
        int o = og * 8 + oo;
#pragma unroll
        for (int r = 0; r < 4; ++r)
            h1[(pb[r] * 32 + o) * 961 + py[r] * 31 + px[r]] = acc[r][oo];
    }
    // fused channel stats: wave-reduce then one atomic pair per wave per o
#pragma unroll 1
    for (int oo = 0; oo < 8; ++oo) {
        float s = 0.f, s2 = 0.f;
#pragma unroll
        for (int r = 0; r < 4; ++r) {
            float a = acc[r][oo];
            s += a; s2 += a * a;
        }
#pragma unroll
        for (int off = 32; off > 0; off >>= 1) {
            s  += __shfl_down(s, off, 64);
            s2 += __shfl_down(s2, off, 64);
        }
        if (lane == 0) {
            int o = og * 8 + oo;
            atomicAdd(&stats[2 * o], s);
            atomicAdd(&stats[2 * o + 1], s2);
        }
    }
}

// ---------- conv2: pooled1 [1024,32,15,15] -> h2 [1024,64,14,14], + stats ----------
// 200704 patches, 256/block, 784 blocks. K-loop over 32 channels, W slice in LDS (dbuf).

__global__ __launch_bounds__(256) void conv2_kernel(
        const float* __restrict__ p1, const float* __restrict__ bw,
        const float* __restrict__ sw, float* __restrict__ h2,
        float* __restrict__ stats) {
    __shared__ float Wl[2][64 * 20];  // [o][kk], stride 80B (b128-aligned)
    int lane = threadIdx.x & 63, og = threadIdx.x >> 6;  // og: 16 outputs each
    int pbase = blockIdx.x * 256 + lane;
    int pb[4], py[4], px[4], qq[4];
#pragma unroll
    for (int r = 0; r < 4; ++r) {
        int p = pbase + 64 * r;
        pb[r] = p / 196;
        int q = p - pb[r] * 196;
        qq[r] = q;
        py[r] = q / 14;
        px[r] = q - py[r] * 14;
    }
    float acc[4][16];
#pragma unroll
    for (int r = 0; r < 4; ++r)
#pragma unroll
        for (int oo = 0; oo < 16; ++oo) acc[r][oo] = 0.0f;

#pragma unroll 1
    for (int c = 0; c < 32; ++c) {
        // issue window loads early (independent of LDS)
        float v[4][4];
#pragma unroll
        for (int r = 0; r < 4; ++r) {
            const float* pc = p1 + (pb[r] * 32 + c) * 225 + py[r] * 15 + px[r];
#pragma unroll
            for (int s = 0; s < 4; ++s)
                v[r][s] = pc[(s >> 1) * 15 + (s & 1)];
        }
        // stage this channel's weight slice [64][20] into LDS (double-buffered)
        float* Wb = Wl[c & 1];
        for (int j = threadIdx.x; j < 1280; j += 256) {
            int o = j / 20;
            int kk = j - o * 20;
            Wb[j] = (kk < 4) ? bw[o * 128 + c * 4 + kk]
                             : sw[o * 512 + c * 16 + kk - 4];
        }
        __syncthreads();
        // expand: e[kk<4] = silu(v_s), e[4+s*4+k] = bspline(v_s)[k]
        float e[4][20];
#pragma unroll
        for (int r = 0; r < 4; ++r) {
#pragma unroll
            for (int s = 0; s < 4; ++s) {
                e[r][s] = siluf(v[r][s]);
                float bsp[4];
                bspline4(v[r][s], bsp);
#pragma unroll
                for (int k = 0; k < 4; ++k) e[r][4 + s * 4 + k] = bsp[k];
            }
        }
#pragma unroll
        for (int oo = 0; oo < 16; ++oo) {
            const float* wp = &Wb[(og * 16 + oo) * 20];
            float4 w0 = *(const float4*)(wp);
            float4 w1 = *(const float4*)(wp + 4);
            float4 w2 = *(const float4*)(wp + 8);
            float4 w3 = *(const float4*)(wp + 12);
            float4 w4 = *(const float4*)(wp + 16);
#pragma unroll
            for (int r = 0; r < 4; ++r) {
                float a = acc[r][oo];
                a += e[r][0]  * w0.x + e[r][1]  * w0.y + e[r][2]  * w0.z + e[r][3]  * w0.w;
                a += e[r][4]  * w1.x + e[r][5]  * w1.y + e[r][6]  * w1.z + e[r][7]  * w1.w;
                a += e[r][8]  * w2.x + e[r][9]  * w2.y + e[r][10] * w2.z + e[r][11] * w2.w;
                a += e[r][12] * w3.x + e[r][13] * w3.y + e[r][14] * w3.z + e[r][15] * w3.w;
                a += e[r][16] * w4.x + e[r][17] * w4.y + e[r][18] * w4.z + e[r][19] * w4.w;
                acc[r][oo] = a;
            }
        }
    }

    // write h2
#pragma unroll
    for (int oo = 0; oo < 16; ++oo) {
        int o = og * 16 + oo;
#pragma unroll
        for (int r = 0; r < 4; ++r)
            h2[(pb[r] * 64 + o) * 196 + qq[r]] = acc[r][oo];
    }
    // fused channel stats
#pragma unroll 1
    for (int oo = 0; oo < 16; ++oo) {
        float s = 0.f, s2 = 0.f;
#pragma unroll
        for (int r = 0; r < 4; ++r) {
            float a = acc[r][oo];
            s += a; s2 += a * a;
        }
#pragma unroll
        for (int off = 32; off > 0; off >>= 1) {
            s  += __shfl_down(s, off, 64);
            s2 += __shfl_down(s2, off, 64);
        }
        if (lane == 0) {
            int o = og * 16 + oo;
            atomicAdd(&stats[2 * o], s);
            atomicAdd(&stats[2 * o + 1], s2);
        }
    }
}

// ---------- fused BN + ReLU + 2x2 maxpool ----------

__global__ __launch_bounds__(256) void bnpool_kernel(
        const float* __restrict__ h, const float* __restrict__ stats,
        const float* __restrict__ g, const float* __restrict__ bb,
        float* __restrict__ out, int C, int H, int W, int PH, int PW,
        float invN, int total) {
    int t = blockIdx.x * 256 + threadIdx.x;
    if (t >= total) return;
    int px = t % PW;
    int py = (t / PW) % PH;
    int c  = (t / (PW * PH)) % C;
    int b  = t / (PW * PH * C);
    float mean = stats[2 * c] * invN;
    float var  = stats[2 * c + 1] * invN - mean * mean;
    float sc = rsqrtf(var + BN_EPS) * g[c];
    float sh = bb[c] - mean * sc;
    const float* hp = h + (((size_t)b * C + c) * H + 2 * py) * W + 2 * px;
    float v0 = fmaxf(hp[0] * sc + sh, 0.f);
    float v1 = fmaxf(hp[1] * sc + sh, 0.f);
    float v2 = fmaxf(hp[W] * sc + sh, 0.f);
    float v3 = fmaxf(hp[W + 1] * sc + sh, 0.f);
    out[t] = fmaxf(fmaxf(v0, v1), fmaxf(v2, v3));
}

// ---------- transpose fc1_w [64,3136] -> wT [3136,64] ----------

__global__ __launch_bounds__(256) void transpose_kernel(
        const float* __restrict__ w, float* __restrict__ wT) {
    int t = blockIdx.x * 256 + threadIdx.x;
    if (t >= 64 * 3136) return;
    int o = t & 63;
    int k = t >> 6;
    wT[(size_t)k * 64 + o] = w[(size_t)o * 3136 + k];
}

// ---------- fc1: pooled2 flat [1024,3136] @ wT -> z [1024,64] ----------

__global__ __launch_bounds__(256) void fc1_kernel(
        const float* __restrict__ xin, const float* __restrict__ wT,
        const float* __restrict__ bias, float* __restrict__ z) {
    __shared__ float xs[4 * 3136];
    __shared__ float red[4][4][64];
    int b0 = blockIdx.x * 4;
    for (int j = threadIdx.x; j < 4 * 3136; j += 256)
        xs[j] = xin[(size_t)b0 * 3136 + j];
    __syncthreads();
    int o = threadIdx.x & 63, q = threadIdx.x >> 6;
    float s0 = 0.f, s1 = 0.f, s2 = 0.f, s3 = 0.f;
    for (int j = q * 784; j < q * 784 + 784; ++j) {
        float wv = wT[(size_t)j * 64 + o];
        s0 += xs[j] * wv;
        s1 += xs[3136 + j] * wv;
        s2 += xs[2 * 3136 + j] * wv;
        s3 += xs[3 * 3136 + j] * wv;
    }
    red[0][q][o] = s0; red[1][q][o] = s1; red[2][q][o] = s2; red[3][q][o] = s3;
    __syncthreads();
    int bb = threadIdx.x >> 6;
    float tot = red[bb][0][o] + red[bb][1][o] + red[bb][2][o] + red[bb][3][o] + bias[o];
    z[((size_t)(b0 + bb)) * 64 + o] = tot;
}

// ---------- bn1d column stats over z [1024,64] ----------

__global__ __launch_bounds__(256) void colstats_kernel(
        const float* __restrict__ z, float* __restrict__ stats) {
    int c = blockIdx.x;
    float s = 0.f, s2 = 0.f;
    for (int b = threadIdx.x; b < 1024; b += 256) {
        float v = z[(size_t)b * 64 + c];
        s += v; s2 += v * v;
    }
#pragma unroll
    for (int off = 32; off > 0; off >>= 1) {
        s  += __shfl_down(s, off, 64);
        s2 += __shfl_down(s2, off, 64);
    }
    __shared__ float ls[8];
    int w = threadIdx.x >> 6;
    if ((threadIdx.x & 63) == 0) { ls[w * 2] = s; ls[w * 2 + 1] = s2; }
    __syncthreads();
    if (threadIdx.x == 0) {
        stats[2 * c]     = ls[0] + ls[2] + ls[4] + ls[6];
        stats[2 * c + 1] = ls[1] + ls[3] + ls[5] + ls[7];
    }
}

// ---------- final: bn1d + relu + fc2 -> out [1024,10] ----------

__global__ __launch_bounds__(256) void final_kernel(
        const float* __restrict__ z, const float* __restrict__ stats,
        const float* __restrict__ g, const float* __restrict__ bb,
        const float* __restrict__ w2, const float* __restrict__ b2,
        float* __restrict__ out) {
    int t = blockIdx.x * 256 + threadIdx.x;
    if (t >= 10240) return;
    int o = t % 10, b = t / 10;
    float acc = b2[o];
#pragma unroll 8
    for (int c = 0; c < 64; ++c) {
        float mean = stats[2 * c] * (1.0f / 1024.0f);
        float var  = stats[2 * c + 1] * (1.0f / 1024.0f) - mean * mean;
        float sc = rsqrtf(var + BN_EPS) * g[c];
        float a = fmaxf(z[(size_t)b * 64 + c] * sc + (bb[c] - mean * sc), 0.f);
        acc += a * w2[o * 64 + c];
    }
    out[t] = acc;
}

// ---------- launch ----------

extern "C" void kernel_launch(void* const* d_in, const int* in_sizes, int n_in,
                              void* d_out, int out_size, void* d_ws, size_t ws_size,
                              hipStream_t stream) {
    const float* x   = (const float*)d_in[0];
    const float* bw1 = (const float*)d_in[1];
    const float* sw1 = (const float*)d_in[2];
    const float* g1  = (const float*)d_in[3];
    const float* b1  = (const float*)d_in[4];
    const float* bw2 = (const float*)d_in[5];
    const float* sw2 = (const float*)d_in[6];
    const float* g2  = (const float*)d_in[7];
    const float* b2v = (const float*)d_in[8];
    const float* fw1 = (const float*)d_in[9];
    const float* fb1 = (const float*)d_in[10];
    const float* g3  = (const float*)d_in[11];
    const float* b3  = (const float*)d_in[12];
    const float* fw2 = (const float*)d_in[13];
    const float* fb2 = (const float*)d_in[14];
    float* out = (float*)d_out;

    char* ws = (char*)d_ws;
    // region A: h1 [1024,32,31,31] (126 MB), reused as h2 [1024,64,14,14]
    float* h1     = (float*)(ws);
    // region B: pooled1 [1024,32,15,15] (29.5 MB), reused as pooled2 [1024,64,7,7]
    float* pooled = (float*)(ws + 125960192);
    float* z      = (float*)(ws + 155451392);   // [1024,64]
    float* wT     = (float*)(ws + 155713536);   // [3136,64]
    float* stats1 = (float*)(ws + 156516352);   // 32*2 floats
    float* stats2 = (float*)(ws + 156516608);   // 64*2 floats
    float* stats3 = (float*)(ws + 156517120);   // 64*2 floats

    hipMemsetAsync(ws + 156516352, 0, 1280, stream);

    transpose_kernel<<<(64 * 3136 + 255) / 256, 256, 0, stream>>>(fw1, wT);

    conv1_kernel<<<3844, 256, 0, stream>>>(x, bw1, sw1, h1, stats1);

    bnpool_kernel<<<(1024 * 32 * 225 + 255) / 256, 256, 0, stream>>>(
        h1, stats1, g1, b1, pooled, 32, 31, 31, 15, 15,
        1.0f / (1024.0f * 961.0f), 1024 * 32 * 225);

    float* h2 = h1;  // region A reuse
    conv2_kernel<<<784, 256, 0, stream>>>(pooled, bw2, sw2, h2, stats2);

    float* pooled2 = pooled;  // region B reuse
    bnpool_kernel<<<(1024 * 64 * 49 + 255) / 256, 256, 0, stream>>>(
        h2, stats2, g2, b2v, pooled2, 64, 14, 14, 7, 7,
        1.0f / (1024.0f * 196.0f), 1024 * 64 * 49);

    fc1_kernel<<<256, 256, 0, stream>>>(pooled2, wT, fb1, z);
    colstats_kernel<<<64, 256, 0, stream>>>(z, stats3);
    final_kernel<<<(10240 + 255) / 256, 256, 0, stream>>>(z, stats3, g3, b3, fw2, fb2, out);
}

// Round 3
// 909.078 us; speedup vs baseline: 3.7270x; 3.7270x over previous
//
#include <hip/hip_runtime.h>
#include <math.h>

#define BN_EPS 1e-5f

// ---------- helpers ----------

__device__ __forceinline__ float siluf(float v) {
    return v / (1.0f + __expf(-v));
}

// Cubic B-spline basis (4 funcs) on uniform knots g[j] = 2*j - 7, j=0..7.
// Closed form: x in knot interval j = floor((x+7)/2), local t in [0,1).
__device__ __forceinline__ void bspline4(float x, float b[4]) {
    float u = (x + 7.0f) * 0.5f;
    float jf = floorf(u);
    float t = u - jf;
    float t2 = t * t, t3 = t2 * t;
    float omt = 1.0f - t;
    float v0 = t3 * (1.0f / 6.0f);
    float v1 = (-3.0f * t3 + 3.0f * t2 + 3.0f * t + 1.0f) * (1.0f / 6.0f);
    float v2 = (3.0f * t3 - 6.0f * t2 + 4.0f) * (1.0f / 6.0f);
    float v3 = omt * omt * omt * (1.0f / 6.0f);
    int j = (int)jf;
#pragma unroll
    for (int i = 0; i < 4; ++i) {
        int d = j - i;
        b[i] = (d == 0) ? v0 : (d == 1) ? v1 : (d == 2) ? v2 : (d == 3) ? v3 : 0.0f;
    }
}

// ---------- conv1: [1024,3,32,32] -> h1 [1024,32,31,31] + block partial stats ----------
// 3844 blocks x 256 thr; each lane owns 4 patches (stride 64), each wave 8 outputs.

__global__ __launch_bounds__(256, 4) void conv1_kernel(
        const float* __restrict__ x, const float* __restrict__ bw,
        const float* __restrict__ sw, float* __restrict__ h1,
        float* __restrict__ part) {
    __shared__ float Wl[12 * 32 * 8];  // [i][o][k(5 pad 8)] = 12 KB
    for (int j = threadIdx.x; j < 12 * 32 * 5; j += 256) {
        int i = j / 160;
        int r = j - i * 160;
        int o = r / 5;
        int k = r - o * 5;
        Wl[(i * 32 + o) * 8 + k] = (k == 0) ? bw[o * 12 + i]
                                            : sw[(o * 12 + i) * 4 + k - 1];
    }
    __syncthreads();

    int lane = threadIdx.x & 63, og = threadIdx.x >> 6;
    int pbase = blockIdx.x * 256 + lane;
    int pb[4], py[4], px[4];
#pragma unroll
    for (int r = 0; r < 4; ++r) {
        int p = pbase + 64 * r;
        pb[r] = p / 961;
        int q = p - pb[r] * 961;
        py[r] = q / 31;
        px[r] = q - py[r] * 31;
    }
    float acc[4][8];
#pragma unroll
    for (int r = 0; r < 4; ++r)
#pragma unroll
        for (int oo = 0; oo < 8; ++oo) acc[r][oo] = 0.0f;

#pragma unroll 1
    for (int i = 0; i < 12; ++i) {
        int c = i >> 2, dy = (i >> 1) & 1, dx = i & 1;
        float v[4];
#pragma unroll
        for (int r = 0; r < 4; ++r)
            v[r] = x[(pb[r] * 3 + c) * 1024 + (py[r] + dy) * 32 + px[r] + dx];
        float e[4][5];
#pragma unroll
        for (int r = 0; r < 4; ++r) {
            e[r][0] = siluf(v[r]);
            bspline4(v[r], &e[r][1]);
        }
#pragma unroll
        for (int oo = 0; oo < 8; ++oo) {
            const float* wp = &Wl[(i * 32 + og * 8 + oo) * 8];
            float4 w0 = *(const float4*)wp;
            float w4v = wp[4];
#pragma unroll
            for (int r = 0; r < 4; ++r) {
                acc[r][oo] += e[r][0] * w0.x + e[r][1] * w0.y + e[r][2] * w0.z
                            + e[r][3] * w0.w + e[r][4] * w4v;
            }
        }
    }

#pragma unroll
    for (int oo = 0; oo < 8; ++oo) {
        int o = og * 8 + oo;
#pragma unroll
        for (int r = 0; r < 4; ++r)
            h1[(pb[r] * 32 + o) * 961 + py[r] * 31 + px[r]] = acc[r][oo];
    }
    // per-wave partial stats -> deterministic per-block scratch (no atomics)
#pragma unroll 1
    for (int oo = 0; oo < 8; ++oo) {
        float s = 0.f, s2 = 0.f;
#pragma unroll
        for (int r = 0; r < 4; ++r) {
            float a = acc[r][oo];
            s += a; s2 += a * a;
        }
#pragma unroll
        for (int off = 32; off > 0; off >>= 1) {
            s  += __shfl_down(s, off, 64);
            s2 += __shfl_down(s2, off, 64);
        }
        if (lane == 0) {
            int o = og * 8 + oo;
            part[(size_t)(2 * o) * 3844 + blockIdx.x]     = s;
            part[(size_t)(2 * o + 1) * 3844 + blockIdx.x] = s2;
        }
    }
}

// ---------- conv2: pooled1 [1024,32,15,15] -> h2 [1024,64,14,14] + partial stats ----------
// 1568 blocks x 256 thr; each lane owns 2 patches, each wave 16 outputs.
// Per-channel weight slice [4s][64o][5k pad8] staged in LDS (8 KB).

__global__ __launch_bounds__(256, 4) void conv2_kernel(
        const float* __restrict__ p1, const float* __restrict__ bw,
        const float* __restrict__ sw, float* __restrict__ h2,
        float* __restrict__ part) {
    __shared__ float Wl[4 * 64 * 8];  // 8 KB
    int lane = threadIdx.x & 63, og = threadIdx.x >> 6;
    int pbase = blockIdx.x * 128 + lane;
    int pb[2], qq[2], py[2], px[2];
#pragma unroll
    for (int r = 0; r < 2; ++r) {
        int p = pbase + 64 * r;
        pb[r] = p / 196;
        int q = p - pb[r] * 196;
        qq[r] = q;
        py[r] = q / 14;
        px[r] = q - py[r] * 14;
    }
    // staging decomposition: 1280 words, 5 consecutive per thread
    int e0i = threadIdx.x * 5;
    int o_st = e0i / 20;
    int s_st = (e0i % 20) / 5;

    float acc[2][16];
#pragma unroll
    for (int r = 0; r < 2; ++r)
#pragma unroll
        for (int oo = 0; oo < 16; ++oo) acc[r][oo] = 0.0f;

#pragma unroll 1
    for (int c = 0; c < 32; ++c) {
        // window loads (independent of LDS) issued first
        float v[2][4];
#pragma unroll
        for (int r = 0; r < 2; ++r) {
            const float* pc = p1 + (pb[r] * 32 + c) * 225 + py[r] * 15 + px[r];
#pragma unroll
            for (int s = 0; s < 4; ++s)
                v[r][s] = pc[(s >> 1) * 15 + (s & 1)];
        }
        // prefetch this channel's weight slice into regs before the barrier
        float t0 = bw[o_st * 128 + c * 4 + s_st];
        float t1 = sw[o_st * 512 + c * 16 + s_st * 4 + 0];
        float t2 = sw[o_st * 512 + c * 16 + s_st * 4 + 1];
        float t3 = sw[o_st * 512 + c * 16 + s_st * 4 + 2];
        float t4 = sw[o_st * 512 + c * 16 + s_st * 4 + 3];
        __syncthreads();   // waves done reading previous channel's slice
        {
            float* wp = &Wl[(s_st * 64 + o_st) * 8];
            wp[0] = t0; wp[1] = t1; wp[2] = t2; wp[3] = t3; wp[4] = t4;
        }
        __syncthreads();
        // process the 4 window positions sequentially (small live set)
#pragma unroll 1
        for (int s = 0; s < 4; ++s) {
            float e[2][5];
#pragma unroll
            for (int r = 0; r < 2; ++r) {
                e[r][0] = siluf(v[r][s]);
                bspline4(v[r][s], &e[r][1]);
            }
#pragma unroll
            for (int oo = 0; oo < 16; ++oo) {
                const float* wp = &Wl[(s * 64 + og * 16 + oo) * 8];
                float4 w0 = *(const float4*)wp;
                float w4v = wp[4];
#pragma unroll
                for (int r = 0; r < 2; ++r) {
                    acc[r][oo] += e[r][0] * w0.x + e[r][1] * w0.y + e[r][2] * w0.z
                                + e[r][3] * w0.w + e[r][4] * w4v;
                }
            }
        }
    }

#pragma unroll
    for (int oo = 0; oo < 16; ++oo) {
        int o = og * 16 + oo;
#pragma unroll
        for (int r = 0; r < 2; ++r)
            h2[(pb[r] * 64 + o) * 196 + qq[r]] = acc[r][oo];
    }
#pragma unroll 1
    for (int oo = 0; oo < 16; ++oo) {
        float s = 0.f, s2 = 0.f;
#pragma unroll
        for (int r = 0; r < 2; ++r) {
            float a = acc[r][oo];
            s += a; s2 += a * a;
        }
#pragma unroll
        for (int off = 32; off > 0; off >>= 1) {
            s  += __shfl_down(s, off, 64);
            s2 += __shfl_down(s2, off, 64);
        }
        if (lane == 0) {
            int o = og * 16 + oo;
            part[(size_t)(2 * o) * 1568 + blockIdx.x]     = s;
            part[(size_t)(2 * o + 1) * 1568 + blockIdx.x] = s2;
        }
    }
}

// ---------- reduce per-block partials -> stats ----------

__global__ __launch_bounds__(256) void redstats_kernel(
        const float* __restrict__ part, float* __restrict__ stats, int nblk) {
    int p = blockIdx.x;
    const float* src = part + (size_t)p * nblk;
    float s = 0.f;
    for (int j = threadIdx.x; j < nblk; j += 256) s += src[j];
#pragma unroll
    for (int off = 32; off > 0; off >>= 1) s += __shfl_down(s, off, 64);
    __shared__ float ls[4];
    if ((threadIdx.x & 63) == 0) ls[threadIdx.x >> 6] = s;
    __syncthreads();
    if (threadIdx.x == 0) stats[p] = ls[0] + ls[1] + ls[2] + ls[3];
}

// ---------- fused BN + ReLU + 2x2 maxpool ----------

__global__ __launch_bounds__(256) void bnpool_kernel(
        const float* __restrict__ h, const float* __restrict__ stats,
        const float* __restrict__ g, const float* __restrict__ bb,
        float* __restrict__ out, int C, int H, int W, int PH, int PW,
        float invN, int total) {
    int t = blockIdx.x * 256 + threadIdx.x;
    if (t >= total) return;
    int px = t % PW;
    int py = (t / PW) % PH;
    int c  = (t / (PW * PH)) % C;
    int b  = t / (PW * PH * C);
    float mean = stats[2 * c] * invN;
    float var  = stats[2 * c + 1] * invN - mean * mean;
    float sc = rsqrtf(var + BN_EPS) * g[c];
    float sh = bb[c] - mean * sc;
    const float* hp = h + (((size_t)b * C + c) * H + 2 * py) * W + 2 * px;
    float v0 = fmaxf(hp[0] * sc + sh, 0.f);
    float v1 = fmaxf(hp[1] * sc + sh, 0.f);
    float v2 = fmaxf(hp[W] * sc + sh, 0.f);
    float v3 = fmaxf(hp[W + 1] * sc + sh, 0.f);
    out[t] = fmaxf(fmaxf(v0, v1), fmaxf(v2, v3));
}

// ---------- transpose fc1_w [64,3136] -> wT [3136,64] ----------

__global__ __launch_bounds__(256) void transpose_kernel(
        const float* __restrict__ w, float* __restrict__ wT) {
    int t = blockIdx.x * 256 + threadIdx.x;
    if (t >= 64 * 3136) return;
    int o = t & 63;
    int k = t >> 6;
    wT[(size_t)k * 64 + o] = w[(size_t)o * 3136 + k];
}

// ---------- fc1: pooled2 flat [1024,3136] @ wT -> z [1024,64] ----------

__global__ __launch_bounds__(256) void fc1_kernel(
        const float* __restrict__ xin, const float* __restrict__ wT,
        const float* __restrict__ bias, float* __restrict__ z) {
    __shared__ float xs[4 * 3136];
    __shared__ float red[4][4][64];
    int b0 = blockIdx.x * 4;
    for (int j = threadIdx.x; j < 4 * 3136; j += 256)
        xs[j] = xin[(size_t)b0 * 3136 + j];
    __syncthreads();
    int o = threadIdx.x & 63, q = threadIdx.x >> 6;
    float s0 = 0.f, s1 = 0.f, s2 = 0.f, s3 = 0.f;
    for (int j = q * 784; j < q * 784 + 784; ++j) {
        float wv = wT[(size_t)j * 64 + o];
        s0 += xs[j] * wv;
        s1 += xs[3136 + j] * wv;
        s2 += xs[2 * 3136 + j] * wv;
        s3 += xs[3 * 3136 + j] * wv;
    }
    red[0][q][o] = s0; red[1][q][o] = s1; red[2][q][o] = s2; red[3][q][o] = s3;
    __syncthreads();
    int bb = threadIdx.x >> 6;
    float tot = red[bb][0][o] + red[bb][1][o] + red[bb][2][o] + red[bb][3][o] + bias[o];
    z[((size_t)(b0 + bb)) * 64 + o] = tot;
}

// ---------- bn1d column stats over z [1024,64] ----------

__global__ __launch_bounds__(256) void colstats_kernel(
        const float* __restrict__ z, float* __restrict__ stats) {
    int c = blockIdx.x;
    float s = 0.f, s2 = 0.f;
    for (int b = threadIdx.x; b < 1024; b += 256) {
        float v = z[(size_t)b * 64 + c];
        s += v; s2 += v * v;
    }
#pragma unroll
    for (int off = 32; off > 0; off >>= 1) {
        s  += __shfl_down(s, off, 64);
        s2 += __shfl_down(s2, off, 64);
    }
    __shared__ float ls[8];
    int w = threadIdx.x >> 6;
    if ((threadIdx.x & 63) == 0) { ls[w * 2] = s; ls[w * 2 + 1] = s2; }
    __syncthreads();
    if (threadIdx.x == 0) {
        stats[2 * c]     = ls[0] + ls[2] + ls[4] + ls[6];
        stats[2 * c + 1] = ls[1] + ls[3] + ls[5] + ls[7];
    }
}

// ---------- final: bn1d + relu + fc2 -> out [1024,10] ----------

__global__ __launch_bounds__(256) void final_kernel(
        const float* __restrict__ z, const float* __restrict__ stats,
        const float* __restrict__ g, const float* __restrict__ bb,
        const float* __restrict__ w2, const float* __restrict__ b2,
        float* __restrict__ out) {
    int t = blockIdx.x * 256 + threadIdx.x;
    if (t >= 10240) return;
    int o = t % 10, b = t / 10;
    float acc = b2[o];
#pragma unroll 8
    for (int c = 0; c < 64; ++c) {
        float mean = stats[2 * c] * (1.0f / 1024.0f);
        float var  = stats[2 * c + 1] * (1.0f / 1024.0f) - mean * mean;
        float sc = rsqrtf(var + BN_EPS) * g[c];
        float a = fmaxf(z[(size_t)b * 64 + c] * sc + (bb[c] - mean * sc), 0.f);
        acc += a * w2[o * 64 + c];
    }
    out[t] = acc;
}

// ---------- launch ----------

extern "C" void kernel_launch(void* const* d_in, const int* in_sizes, int n_in,
                              void* d_out, int out_size, void* d_ws, size_t ws_size,
                              hipStream_t stream) {
    const float* x   = (const float*)d_in[0];
    const float* bw1 = (const float*)d_in[1];
    const float* sw1 = (const float*)d_in[2];
    const float* g1  = (const float*)d_in[3];
    const float* b1  = (const float*)d_in[4];
    const float* bw2 = (const float*)d_in[5];
    const float* sw2 = (const float*)d_in[6];
    const float* g2  = (const float*)d_in[7];
    const float* b2v = (const float*)d_in[8];
    const float* fw1 = (const float*)d_in[9];
    const float* fb1 = (const float*)d_in[10];
    const float* g3  = (const float*)d_in[11];
    const float* b3  = (const float*)d_in[12];
    const float* fw2 = (const float*)d_in[13];
    const float* fb2 = (const float*)d_in[14];
    float* out = (float*)d_out;

    char* ws = (char*)d_ws;
    // region A [0, 126 MB): h1 [1024,32,31,31]; later h2 [1024,64,14,14] (51.4 MB)
    //   + part2 tucked after h2 at +51,380,224 (0.8 MB) during conv2
    float* h1     = (float*)(ws);
    float* part2  = (float*)(ws + 51380224);
    // region B [126 MB, 155.5 MB): pooled1 [1024,32,15,15]; later pooled2.
    //   part1 aliases region B during conv1 (read back before bnpool1 writes pooled1)
    float* pooled = (float*)(ws + 125960192);
    float* part1  = (float*)(ws + 125960192);
    float* z      = (float*)(ws + 155451392);   // [1024,64]
    float* wT     = (float*)(ws + 155713536);   // [3136,64]
    float* stats1 = (float*)(ws + 156516352);   // 64 floats
    float* stats2 = (float*)(ws + 156516608);   // 128 floats
    float* stats3 = (float*)(ws + 156517120);   // 128 floats

    transpose_kernel<<<(64 * 3136 + 255) / 256, 256, 0, stream>>>(fw1, wT);

    conv1_kernel<<<3844, 256, 0, stream>>>(x, bw1, sw1, h1, part1);
    redstats_kernel<<<64, 256, 0, stream>>>(part1, stats1, 3844);

    bnpool_kernel<<<(1024 * 32 * 225 + 255) / 256, 256, 0, stream>>>(
        h1, stats1, g1, b1, pooled, 32, 31, 31, 15, 15,
        1.0f / (1024.0f * 961.0f), 1024 * 32 * 225);

    float* h2 = h1;  // region A reuse
    conv2_kernel<<<1568, 256, 0, stream>>>(pooled, bw2, sw2, h2, part2);
    redstats_kernel<<<128, 256, 0, stream>>>(part2, stats2, 1568);

    float* pooled2 = pooled;  // region B reuse
    bnpool_kernel<<<(1024 * 64 * 49 + 255) / 256, 256, 0, stream>>>(
        h2, stats2, g2, b2v, pooled2, 64, 14, 14, 7, 7,
        1.0f / (1024.0f * 196.0f), 1024 * 64 * 49);

    fc1_kernel<<<256, 256, 0, stream>>>(pooled2, wT, fb1, z);
    colstats_kernel<<<64, 256, 0, stream>>>(z, stats3);
    final_kernel<<<(10240 + 255) / 256, 256, 0, stream>>>(z, stats3, g3, b3, fw2, fb2, out);
}